// Round 1
// baseline (6899.689 us; speedup 1.0000x reference)
//
#include <hip/hip_runtime.h>
#include <hip/hip_bf16.h>
#include <hip/hip_cooperative_groups.h>

namespace cg = cooperative_groups;

typedef __attribute__((ext_vector_type(8))) short short8;
typedef __attribute__((ext_vector_type(4))) float f32x4;

#define S_ 64
#define B_ 64
#define H_ 1024
#define E_ 512
#define V_ 10000
#define M_ 4096          // S_*B_
#define VPAD 10048       // V rounded up to 64

__device__ __forceinline__ float sigmoidf_(float x) {
  return 1.0f / (1.0f + __expf(-x));
}

// ---------------- bias concat: b0cat = [br0,bz0,bh0], b1cat = [br1,bz1,bh1] -------------
__global__ void bias_concat(const float* br0, const float* bz0, const float* bh0,
                            const float* br1, const float* bz1, const float* bh1,
                            float* b0cat, float* b1cat) {
  int i = blockIdx.x * 256 + threadIdx.x;   // 0..3071
  if (i >= 3072) return;
  if (i < 1024)       { b0cat[i] = br0[i];        b1cat[i] = br1[i]; }
  else if (i < 2048)  { b0cat[i] = bz0[i - 1024]; b1cat[i] = bz1[i - 1024]; }
  else                { b0cat[i] = bh0[i - 2048]; b1cat[i] = bh1[i - 2048]; }
}

// ---------------- transpose + cast: dst[c*R + r] = bf16(src[r*C + c]) -------------------
__global__ void transpose_cast(const float* __restrict__ src, __hip_bfloat16* __restrict__ dst,
                               int R, int C) {
  __shared__ float tile[32][33];
  int c0 = blockIdx.x * 32, r0 = blockIdx.y * 32;
  int tx = threadIdx.x & 31, ty = threadIdx.x >> 5;   // 32 x 8
#pragma unroll
  for (int i = 0; i < 4; ++i) {
    int r = r0 + ty + i * 8;
    int c = c0 + tx;
    if (r < R && c < C) tile[ty + i * 8][tx] = src[(size_t)r * C + c];
  }
  __syncthreads();
#pragma unroll
  for (int i = 0; i < 4; ++i) {
    int c = c0 + ty + i * 8;
    int r = r0 + tx;
    if (c < C && r < R) dst[(size_t)c * R + r] = __float2bfloat16(tile[tx][ty + i * 8]);
  }
}

// ---------------- embedding gather + cast to bf16: X0[i][e] = emb[tok[i]][e] ------------
__global__ void embed_cast(const int* __restrict__ inputs, const float* __restrict__ emb,
                           __hip_bfloat16* __restrict__ X0) {
  int idx = blockIdx.x * 256 + threadIdx.x;  // over 4096 * 128 float4 groups
  int i = idx >> 7;
  int e4 = idx & 127;
  int tok = inputs[i];
  const float4* src = (const float4*)(emb + (size_t)tok * E_);
  float4 v = src[e4];
  __hip_bfloat16* dst = X0 + (size_t)i * E_ + e4 * 4;
  dst[0] = __float2bfloat16(v.x);
  dst[1] = __float2bfloat16(v.y);
  dst[2] = __float2bfloat16(v.z);
  dst[3] = __float2bfloat16(v.w);
}

// ---------------- generic bf16 MFMA GEMM: C = act(A[M,K] @ BT[N,K]^T + bias) ------------
// grid = (ceil(N/64), M/64), block = 256 (4 waves, each a 32x32 quadrant of the 64x64 tile)
__global__ __launch_bounds__(256) void gemm_bf16(
    const __hip_bfloat16* __restrict__ A, const __hip_bfloat16* __restrict__ BT,
    const float* __restrict__ bias, void* __restrict__ C,
    int M, int N, int K, int act, int out_bf16) {
  __shared__ unsigned short Al[64 * 72];
  __shared__ unsigned short Bl[64 * 72];
  const int m0 = blockIdx.y * 64, n0 = blockIdx.x * 64;
  const int tid = threadIdx.x;
  const int wave = tid >> 6, lane = tid & 63;
  const int quad = lane >> 4, lr = lane & 15;
  const int wm = (wave >> 1) * 32, wn = (wave & 1) * 32;
  const int srow = tid >> 2, scol = (tid & 3) << 4;

  f32x4 acc[2][2];
#pragma unroll
  for (int a = 0; a < 2; ++a)
#pragma unroll
    for (int b = 0; b < 2; ++b) acc[a][b] = (f32x4){0.f, 0.f, 0.f, 0.f};

  const __hip_bfloat16* Ag = A + (size_t)(m0 + srow) * K + scol;
  const __hip_bfloat16* Bg = BT + (size_t)(n0 + srow) * K + scol;

  for (int kb = 0; kb < K; kb += 64) {
    short8 a0 = *(const short8*)(Ag + kb);
    short8 a1 = *(const short8*)(Ag + kb + 8);
    short8 b0 = *(const short8*)(Bg + kb);
    short8 b1 = *(const short8*)(Bg + kb + 8);
    *(short8*)&Al[srow * 72 + scol] = a0;
    *(short8*)&Al[srow * 72 + scol + 8] = a1;
    *(short8*)&Bl[srow * 72 + scol] = b0;
    *(short8*)&Bl[srow * 72 + scol + 8] = b1;
    __syncthreads();
#pragma unroll
    for (int k2 = 0; k2 < 64; k2 += 32) {
      short8 af0 = *(const short8*)&Al[(wm + lr) * 72 + k2 + quad * 8];
      short8 af1 = *(const short8*)&Al[(wm + 16 + lr) * 72 + k2 + quad * 8];
      short8 bf0 = *(const short8*)&Bl[(wn + lr) * 72 + k2 + quad * 8];
      short8 bf1 = *(const short8*)&Bl[(wn + 16 + lr) * 72 + k2 + quad * 8];
      acc[0][0] = __builtin_amdgcn_mfma_f32_16x16x32_bf16(af0, bf0, acc[0][0], 0, 0, 0);
      acc[0][1] = __builtin_amdgcn_mfma_f32_16x16x32_bf16(af0, bf1, acc[0][1], 0, 0, 0);
      acc[1][0] = __builtin_amdgcn_mfma_f32_16x16x32_bf16(af1, bf0, acc[1][0], 0, 0, 0);
      acc[1][1] = __builtin_amdgcn_mfma_f32_16x16x32_bf16(af1, bf1, acc[1][1], 0, 0, 0);
    }
    __syncthreads();
  }

#pragma unroll
  for (int mi = 0; mi < 2; ++mi)
#pragma unroll
    for (int ni = 0; ni < 2; ++ni) {
      int n = n0 + wn + ni * 16 + lr;
      if (n >= N) continue;
      float bv = bias ? bias[n] : 0.f;
#pragma unroll
      for (int r = 0; r < 4; ++r) {
        int m = m0 + wm + mi * 16 + quad * 4 + r;
        float v = acc[mi][ni][r] + bv;
        if (act) v = sigmoidf_(v);
        if (out_bf16) ((__hip_bfloat16*)C)[(size_t)m * N + n] = __float2bfloat16(v);
        else          ((float*)C)[(size_t)m * N + n] = v;
      }
    }
}

// ---------------- cooperative GRU recurrence for one layer ------------------------------
// G:   [4096, 3072] fp32 pre-activation x-part (+bias), cols (r, z, hh)
// WT:  [3072, 1024] bf16 transposed h-part weights, rows (r, z, hh)
// 128 blocks x 256 threads. Phase A: all blocks, 16 cols each of rz (2048).
// Phase B: blocks 0..63, 16 cols each of hh (1024).
__global__ __launch_bounds__(256) void gru_recurrent(
    const float* __restrict__ G, const __hip_bfloat16* __restrict__ WT,
    const float* __restrict__ init_h,
    float* __restrict__ h_state, __hip_bfloat16* __restrict__ h_bf,
    __hip_bfloat16* __restrict__ rh_bf, float* __restrict__ z_buf,
    __hip_bfloat16* __restrict__ Hseq, float* __restrict__ h_final) {
  cg::grid_group grid = cg::this_grid();
  const int bid = blockIdx.x;
  const int tid = threadIdx.x;
  const int wave = tid >> 6, lane = tid & 63;
  const int quad = lane >> 4, lr = lane & 15;

  // init h_state / h_bf from init_hidden
  for (int idx = bid * 256 + tid; idx < B_ * H_; idx += 128 * 256) {
    float v = init_h[idx];
    h_state[idx] = v;
    h_bf[idx] = __float2bfloat16(v);
  }
  grid.sync();

  for (int t = 0; t < S_; ++t) {
    // ---- phase A: rz = sigmoid(G_rz[t] + h @ W_rz) ----
    {
      const int nb = bid * 16;
      const int am = wave * 16 + lr;   // A row this lane loads (batch)
      const int bn = nb + lr;          // WT row this lane loads
      f32x4 acc = (f32x4){0.f, 0.f, 0.f, 0.f};
      const __hip_bfloat16* ap = h_bf + (size_t)am * H_ + quad * 8;
      const __hip_bfloat16* bp = WT + (size_t)bn * H_ + quad * 8;
#pragma unroll 4
      for (int kk = 0; kk < 32; ++kk) {
        short8 a = *(const short8*)(ap + kk * 32);
        short8 b = *(const short8*)(bp + kk * 32);
        acc = __builtin_amdgcn_mfma_f32_16x16x32_bf16(a, b, acc, 0, 0, 0);
      }
#pragma unroll
      for (int r = 0; r < 4; ++r) {
        int mm = wave * 16 + quad * 4 + r;
        int nn = nb + lr;
        float val = acc[r] + G[(size_t)(t * B_ + mm) * 3072 + nn];
        val = sigmoidf_(val);
        if (nn < H_) {
          rh_bf[mm * H_ + nn] = __float2bfloat16(val * h_state[mm * H_ + nn]);
        } else {
          z_buf[mm * H_ + (nn - H_)] = val;
        }
      }
    }
    grid.sync();
    // ---- phase B: hh = sigmoid(G_h[t] + (r*h) @ Wh_h); h = (1-z)h + z*hh ----
    if (bid < 64) {
      const int nb = bid * 16;
      const int am = wave * 16 + lr;
      const int bn = 2048 + nb + lr;
      f32x4 acc = (f32x4){0.f, 0.f, 0.f, 0.f};
      const __hip_bfloat16* ap = rh_bf + (size_t)am * H_ + quad * 8;
      const __hip_bfloat16* bp = WT + (size_t)bn * H_ + quad * 8;
#pragma unroll 4
      for (int kk = 0; kk < 32; ++kk) {
        short8 a = *(const short8*)(ap + kk * 32);
        short8 b = *(const short8*)(bp + kk * 32);
        acc = __builtin_amdgcn_mfma_f32_16x16x32_bf16(a, b, acc, 0, 0, 0);
      }
#pragma unroll
      for (int r = 0; r < 4; ++r) {
        int mm = wave * 16 + quad * 4 + r;
        int nn = nb + lr;
        float pre = acc[r] + G[(size_t)(t * B_ + mm) * 3072 + 2048 + nn];
        float hh = sigmoidf_(pre);
        float z = z_buf[mm * H_ + nn];
        float ho = h_state[mm * H_ + nn];
        float hn = ho + z * (hh - ho);
        h_state[mm * H_ + nn] = hn;
        h_bf[mm * H_ + nn] = __float2bfloat16(hn);
        Hseq[(size_t)(t * B_ + mm) * H_ + nn] = __float2bfloat16(hn);
        if (t == S_ - 1) h_final[mm * H_ + nn] = hn;
      }
    }
    grid.sync();
  }
}

// ---------------------------------- host launcher ---------------------------------------
extern "C" void kernel_launch(void* const* d_in, const int* in_sizes, int n_in,
                              void* d_out, int out_size, void* d_ws, size_t ws_size,
                              hipStream_t stream) {
  const int*   inputs      = (const int*)d_in[0];
  const float* init_hidden = (const float*)d_in[1];
  const float* emb         = (const float*)d_in[2];
  const float* Wr0 = (const float*)d_in[3];
  const float* Wz0 = (const float*)d_in[4];
  const float* Wh0 = (const float*)d_in[5];
  const float* br0 = (const float*)d_in[6];
  const float* bz0 = (const float*)d_in[7];
  const float* bh0 = (const float*)d_in[8];
  const float* Wr1 = (const float*)d_in[9];
  const float* Wz1 = (const float*)d_in[10];
  const float* Wh1 = (const float*)d_in[11];
  const float* br1 = (const float*)d_in[12];
  const float* bz1 = (const float*)d_in[13];
  const float* bh1 = (const float*)d_in[14];
  const float* Wfc0 = (const float*)d_in[15];
  const float* bfc0 = (const float*)d_in[16];
  const float* Wout = (const float*)d_in[17];
  const float* bout = (const float*)d_in[18];
  float* out = (float*)d_out;

  // -------- workspace layout --------
  char* ws = (char*)d_ws;
  size_t off = 0;
  auto alloc = [&](size_t bytes) -> char* {
    char* p = ws + off;
    off = (off + bytes + 255) & ~(size_t)255;
    return p;
  };
  __hip_bfloat16* W0xT  = (__hip_bfloat16*)alloc((size_t)3072 * E_ * 2);
  __hip_bfloat16* W0hT  = (__hip_bfloat16*)alloc((size_t)3072 * H_ * 2);
  __hip_bfloat16* WfcT  = (__hip_bfloat16*)alloc((size_t)H_ * H_ * 2);
  __hip_bfloat16* W1xT  = (__hip_bfloat16*)alloc((size_t)3072 * H_ * 2);
  __hip_bfloat16* W1hT  = (__hip_bfloat16*)alloc((size_t)3072 * H_ * 2);
  __hip_bfloat16* WoutT = (__hip_bfloat16*)alloc((size_t)VPAD * H_ * 2);
  float* b0cat = (float*)alloc(3072 * 4);
  float* b1cat = (float*)alloc(3072 * 4);
  __hip_bfloat16* X0    = (__hip_bfloat16*)alloc((size_t)M_ * E_ * 2);
  float* G              = (float*)alloc((size_t)M_ * 3072 * 4);
  __hip_bfloat16* Hseq0 = (__hip_bfloat16*)alloc((size_t)M_ * H_ * 2);
  __hip_bfloat16* X1    = (__hip_bfloat16*)alloc((size_t)M_ * H_ * 2);
  __hip_bfloat16* Hseq1 = (__hip_bfloat16*)alloc((size_t)M_ * H_ * 2);
  float* hs0 = (float*)alloc((size_t)B_ * H_ * 4);
  float* hs1 = (float*)alloc((size_t)B_ * H_ * 4);
  __hip_bfloat16* hb0 = (__hip_bfloat16*)alloc((size_t)B_ * H_ * 2);
  __hip_bfloat16* hb1 = (__hip_bfloat16*)alloc((size_t)B_ * H_ * 2);
  __hip_bfloat16* rh  = (__hip_bfloat16*)alloc((size_t)B_ * H_ * 2);
  float* zb = (float*)alloc((size_t)B_ * H_ * 4);
  (void)ws_size; (void)n_in; (void)in_sizes; (void)out_size;

  // -------- prep: biases, transposed bf16 weights, embedding --------
  hipLaunchKernelGGL(bias_concat, dim3(12), dim3(256), 0, stream,
                     br0, bz0, bh0, br1, bz1, bh1, b0cat, b1cat);

  auto tp = [&](const float* src, __hip_bfloat16* dst, int R, int C) {
    hipLaunchKernelGGL(transpose_cast, dim3((C + 31) / 32, (R + 31) / 32), dim3(256), 0,
                       stream, src, dst, R, C);
  };
  // layer 0 x-part [E,H] -> [3H, E]
  tp(Wr0,            W0xT,                E_, H_);
  tp(Wz0,            W0xT + 1024 * E_,    E_, H_);
  tp(Wh0,            W0xT + 2048 * E_,    E_, H_);
  // layer 0 h-part
  tp(Wr0 + (size_t)E_ * H_, W0hT,               H_, H_);
  tp(Wz0 + (size_t)E_ * H_, W0hT + 1024 * H_,   H_, H_);
  tp(Wh0 + (size_t)E_ * H_, W0hT + 2048 * H_,   H_, H_);
  // fc
  tp(Wfc0, WfcT, H_, H_);
  // layer 1 x-part
  tp(Wr1,            W1xT,                H_, H_);
  tp(Wz1,            W1xT + 1024 * H_,    H_, H_);
  tp(Wh1,            W1xT + 2048 * H_,    H_, H_);
  // layer 1 h-part
  tp(Wr1 + (size_t)H_ * H_, W1hT,               H_, H_);
  tp(Wz1 + (size_t)H_ * H_, W1hT + 1024 * H_,   H_, H_);
  tp(Wh1 + (size_t)H_ * H_, W1hT + 2048 * H_,   H_, H_);
  // out projection [H,V] -> [Vpad, H] (rows >= V left as poison, guarded at GEMM store)
  tp(Wout, WoutT, H_, V_);

  hipLaunchKernelGGL(embed_cast, dim3(M_ * (E_ / 4) / 256), dim3(256), 0, stream,
                     inputs, emb, X0);

  // -------- G0 = X0 @ W0x + b0cat  (fp32 [4096,3072]) --------
  hipLaunchKernelGGL(gemm_bf16, dim3(3072 / 64, M_ / 64), dim3(256), 0, stream,
                     X0, W0xT, b0cat, (void*)G, M_, 3072, E_, 0, 0);

  // -------- layer 0 recurrence --------
  {
    const float* Gp = G; const __hip_bfloat16* WTp = W0hT;
    const float* inith = init_hidden;                 // layer 0 slice
    float* hsp = hs0; __hip_bfloat16* hbp = hb0; __hip_bfloat16* rhp = rh;
    float* zbp = zb; __hip_bfloat16* Hsp = Hseq0;
    float* hfin = out + (size_t)M_ * V_;              // h_final layer 0
    void* kargs[] = {(void*)&Gp, (void*)&WTp, (void*)&inith, (void*)&hsp, (void*)&hbp,
                     (void*)&rhp, (void*)&zbp, (void*)&Hsp, (void*)&hfin};
    hipLaunchCooperativeKernel((const void*)gru_recurrent, dim3(128), dim3(256),
                               kargs, 0, stream);
  }

  // -------- X1 = sigmoid(Hseq0 @ Wfc + bfc)  (bf16 [4096,1024]) --------
  hipLaunchKernelGGL(gemm_bf16, dim3(H_ / 64, M_ / 64), dim3(256), 0, stream,
                     Hseq0, WfcT, bfc0, (void*)X1, M_, H_, H_, 1, 1);

  // -------- G1 = X1 @ W1x + b1cat  (fp32 [4096,3072]) --------
  hipLaunchKernelGGL(gemm_bf16, dim3(3072 / 64, M_ / 64), dim3(256), 0, stream,
                     X1, W1xT, b1cat, (void*)G, M_, 3072, H_, 0, 0);

  // -------- layer 1 recurrence --------
  {
    const float* Gp = G; const __hip_bfloat16* WTp = W1hT;
    const float* inith = init_hidden + (size_t)B_ * H_;   // layer 1 slice
    float* hsp = hs1; __hip_bfloat16* hbp = hb1; __hip_bfloat16* rhp = rh;
    float* zbp = zb; __hip_bfloat16* Hsp = Hseq1;
    float* hfin = out + (size_t)M_ * V_ + (size_t)B_ * H_;  // h_final layer 1
    void* kargs[] = {(void*)&Gp, (void*)&WTp, (void*)&inith, (void*)&hsp, (void*)&hbp,
                     (void*)&rhp, (void*)&zbp, (void*)&Hsp, (void*)&hfin};
    hipLaunchCooperativeKernel((const void*)gru_recurrent, dim3(128), dim3(256),
                               kargs, 0, stream);
  }

  // -------- logits = Hseq1 @ Wout + bout  (fp32 [4096,10000] straight into d_out) -------
  hipLaunchKernelGGL(gemm_bf16, dim3(VPAD / 64, M_ / 64), dim3(256), 0, stream,
                     Hseq1, WoutT, bout, (void*)out, M_, V_, H_, 0, 0);
}

// Round 2
// 5856.557 us; speedup vs baseline: 1.1781x; 1.1781x over previous
//
#include <hip/hip_runtime.h>
#include <hip/hip_bf16.h>

typedef __attribute__((ext_vector_type(8))) short short8;
typedef __attribute__((ext_vector_type(4))) float f32x4;

#define S_ 64
#define B_ 64
#define H_ 1024
#define E_ 512
#define V_ 10000
#define M_ 4096          // S_*B_
#define VPAD 10048       // V rounded up to 64
#define NBLK 128

__device__ __forceinline__ float sigmoidf_(float x) {
  return 1.0f / (1.0f + __expf(-x));
}

// ---- fast device-scope grid barrier --------------------------------------------------
// cnt: never-reset arrival counter; gen: generation flag. idx must increase by exactly
// 1 per barrier call, uniform across blocks. Requires all blocks co-resident.
__device__ __forceinline__ void gbar(int* cnt, int* gen, int idx) {
  __syncthreads();
  if (threadIdx.x == 0) {
    __threadfence();  // release: make prior global writes visible device-wide
    int a = __hip_atomic_fetch_add(cnt, 1, __ATOMIC_RELAXED, __HIP_MEMORY_SCOPE_AGENT) + 1;
    if (a == NBLK * idx) {
      __hip_atomic_store(gen, idx, __ATOMIC_RELEASE, __HIP_MEMORY_SCOPE_AGENT);
    } else {
      while (__hip_atomic_load(gen, __ATOMIC_ACQUIRE, __HIP_MEMORY_SCOPE_AGENT) < idx) {
        __builtin_amdgcn_s_sleep(1);
      }
    }
    __threadfence();  // acquire side
  }
  __syncthreads();
}

// ---------------- bias concat: b0cat = [br0,bz0,bh0], b1cat = [br1,bz1,bh1] -------------
__global__ void bias_concat(const float* br0, const float* bz0, const float* bh0,
                            const float* br1, const float* bz1, const float* bh1,
                            float* b0cat, float* b1cat) {
  int i = blockIdx.x * 256 + threadIdx.x;   // 0..3071
  if (i >= 3072) return;
  if (i < 1024)       { b0cat[i] = br0[i];        b1cat[i] = br1[i]; }
  else if (i < 2048)  { b0cat[i] = bz0[i - 1024]; b1cat[i] = bz1[i - 1024]; }
  else                { b0cat[i] = bh0[i - 2048]; b1cat[i] = bh1[i - 2048]; }
}

// ---------------- transpose + cast: dst[c*R + r] = bf16(src[r*C + c]) -------------------
__global__ void transpose_cast(const float* __restrict__ src, __hip_bfloat16* __restrict__ dst,
                               int R, int C) {
  __shared__ float tile[32][33];
  int c0 = blockIdx.x * 32, r0 = blockIdx.y * 32;
  int tx = threadIdx.x & 31, ty = threadIdx.x >> 5;   // 32 x 8
#pragma unroll
  for (int i = 0; i < 4; ++i) {
    int r = r0 + ty + i * 8;
    int c = c0 + tx;
    if (r < R && c < C) tile[ty + i * 8][tx] = src[(size_t)r * C + c];
  }
  __syncthreads();
#pragma unroll
  for (int i = 0; i < 4; ++i) {
    int c = c0 + ty + i * 8;
    int r = r0 + tx;
    if (c < C && r < R) dst[(size_t)c * R + r] = __float2bfloat16(tile[tx][ty + i * 8]);
  }
}

// ---------------- embedding gather + cast to bf16: X0[i][e] = emb[tok[i]][e] ------------
__global__ void embed_cast(const int* __restrict__ inputs, const float* __restrict__ emb,
                           __hip_bfloat16* __restrict__ X0) {
  int idx = blockIdx.x * 256 + threadIdx.x;  // over 4096 * 128 float4 groups
  int i = idx >> 7;
  int e4 = idx & 127;
  int tok = inputs[i];
  const float4* src = (const float4*)(emb + (size_t)tok * E_);
  float4 v = src[e4];
  __hip_bfloat16* dst = X0 + (size_t)i * E_ + e4 * 4;
  dst[0] = __float2bfloat16(v.x);
  dst[1] = __float2bfloat16(v.y);
  dst[2] = __float2bfloat16(v.z);
  dst[3] = __float2bfloat16(v.w);
}

// ---------------- generic bf16 MFMA GEMM: C = act(A[M,K] @ BT[N,K]^T + bias) ------------
// grid = (ceil(N/64), M/64), block = 256 (4 waves, each a 32x32 quadrant of the 64x64 tile)
__global__ __launch_bounds__(256) void gemm_bf16(
    const __hip_bfloat16* __restrict__ A, const __hip_bfloat16* __restrict__ BT,
    const float* __restrict__ bias, void* __restrict__ C,
    int M, int N, int K, int act, int out_bf16) {
  __shared__ unsigned short Al[64 * 72];
  __shared__ unsigned short Bl[64 * 72];
  const int m0 = blockIdx.y * 64, n0 = blockIdx.x * 64;
  const int tid = threadIdx.x;
  const int wave = tid >> 6, lane = tid & 63;
  const int quad = lane >> 4, lr = lane & 15;
  const int wm = (wave >> 1) * 32, wn = (wave & 1) * 32;
  const int srow = tid >> 2, scol = (tid & 3) << 4;

  f32x4 acc[2][2];
#pragma unroll
  for (int a = 0; a < 2; ++a)
#pragma unroll
    for (int b = 0; b < 2; ++b) acc[a][b] = (f32x4){0.f, 0.f, 0.f, 0.f};

  const __hip_bfloat16* Ag = A + (size_t)(m0 + srow) * K + scol;
  const __hip_bfloat16* Bg = BT + (size_t)(n0 + srow) * K + scol;

  for (int kb = 0; kb < K; kb += 64) {
    short8 a0 = *(const short8*)(Ag + kb);
    short8 a1 = *(const short8*)(Ag + kb + 8);
    short8 b0 = *(const short8*)(Bg + kb);
    short8 b1 = *(const short8*)(Bg + kb + 8);
    *(short8*)&Al[srow * 72 + scol] = a0;
    *(short8*)&Al[srow * 72 + scol + 8] = a1;
    *(short8*)&Bl[srow * 72 + scol] = b0;
    *(short8*)&Bl[srow * 72 + scol + 8] = b1;
    __syncthreads();
#pragma unroll
    for (int k2 = 0; k2 < 64; k2 += 32) {
      short8 af0 = *(const short8*)&Al[(wm + lr) * 72 + k2 + quad * 8];
      short8 af1 = *(const short8*)&Al[(wm + 16 + lr) * 72 + k2 + quad * 8];
      short8 bf0 = *(const short8*)&Bl[(wn + lr) * 72 + k2 + quad * 8];
      short8 bf1 = *(const short8*)&Bl[(wn + 16 + lr) * 72 + k2 + quad * 8];
      acc[0][0] = __builtin_amdgcn_mfma_f32_16x16x32_bf16(af0, bf0, acc[0][0], 0, 0, 0);
      acc[0][1] = __builtin_amdgcn_mfma_f32_16x16x32_bf16(af0, bf1, acc[0][1], 0, 0, 0);
      acc[1][0] = __builtin_amdgcn_mfma_f32_16x16x32_bf16(af1, bf0, acc[1][0], 0, 0, 0);
      acc[1][1] = __builtin_amdgcn_mfma_f32_16x16x32_bf16(af1, bf1, acc[1][1], 0, 0, 0);
    }
    __syncthreads();
  }

#pragma unroll
  for (int mi = 0; mi < 2; ++mi)
#pragma unroll
    for (int ni = 0; ni < 2; ++ni) {
      int n = n0 + wn + ni * 16 + lr;
      if (n >= N) continue;
      float bv = bias ? bias[n] : 0.f;
#pragma unroll
      for (int r = 0; r < 4; ++r) {
        int m = m0 + wm + mi * 16 + quad * 4 + r;
        float v = acc[mi][ni][r] + bv;
        if (act) v = sigmoidf_(v);
        if (out_bf16) ((__hip_bfloat16*)C)[(size_t)m * N + n] = __float2bfloat16(v);
        else          ((float*)C)[(size_t)m * N + n] = v;
      }
    }
}

// ---------------- cooperative GRU recurrence for one layer ------------------------------
// G:   [4096, 3072] fp32 pre-activation x-part (+bias), cols (r, z, hh)
// WT:  [3072, 1024] bf16 transposed h-part weights, rows (r, z, hh)
// 128 blocks x 256 threads. Phase A: all blocks, 16 cols each of rz (2048).
// Phase B: blocks 0..63, 16 cols each of hh (1024).
__global__ __launch_bounds__(256) void gru_recurrent(
    const float* __restrict__ G, const __hip_bfloat16* __restrict__ WT,
    const float* __restrict__ init_h,
    float* __restrict__ h_state, __hip_bfloat16* __restrict__ h_bf,
    __hip_bfloat16* __restrict__ rh_bf, float* __restrict__ z_buf,
    __hip_bfloat16* __restrict__ Hseq, float* __restrict__ h_final,
    int* __restrict__ bar_cnt, int* __restrict__ bar_gen) {
  const int bid = blockIdx.x;
  const int tid = threadIdx.x;
  const int wave = tid >> 6, lane = tid & 63;
  const int quad = lane >> 4, lr = lane & 15;

  // init h_state / h_bf from init_hidden
  for (int idx = bid * 256 + tid; idx < B_ * H_; idx += 128 * 256) {
    float v = init_h[idx];
    h_state[idx] = v;
    h_bf[idx] = __float2bfloat16(v);
  }
  int bidx = 1;
  gbar(bar_cnt, bar_gen, bidx++);

  for (int t = 0; t < S_; ++t) {
    // ---- phase A: rz = sigmoid(G_rz[t] + h @ W_rz) ----
    {
      const int nb = bid * 16;
      const int am = wave * 16 + lr;   // A row this lane loads (batch)
      const int bn = nb + lr;          // WT row this lane loads
      f32x4 acc = (f32x4){0.f, 0.f, 0.f, 0.f};
      const __hip_bfloat16* ap = h_bf + (size_t)am * H_ + quad * 8;
      const __hip_bfloat16* bp = WT + (size_t)bn * H_ + quad * 8;
#pragma unroll 4
      for (int kk = 0; kk < 32; ++kk) {
        short8 a = *(const short8*)(ap + kk * 32);
        short8 b = *(const short8*)(bp + kk * 32);
        acc = __builtin_amdgcn_mfma_f32_16x16x32_bf16(a, b, acc, 0, 0, 0);
      }
#pragma unroll
      for (int r = 0; r < 4; ++r) {
        int mm = wave * 16 + quad * 4 + r;
        int nn = nb + lr;
        float val = acc[r] + G[(size_t)(t * B_ + mm) * 3072 + nn];
        val = sigmoidf_(val);
        if (nn < H_) {
          rh_bf[mm * H_ + nn] = __float2bfloat16(val * h_state[mm * H_ + nn]);
        } else {
          z_buf[mm * H_ + (nn - H_)] = val;
        }
      }
    }
    gbar(bar_cnt, bar_gen, bidx++);
    // ---- phase B: hh = sigmoid(G_h[t] + (r*h) @ Wh_h); h = (1-z)h + z*hh ----
    if (bid < 64) {
      const int nb = bid * 16;
      const int am = wave * 16 + lr;
      const int bn = 2048 + nb + lr;
      f32x4 acc = (f32x4){0.f, 0.f, 0.f, 0.f};
      const __hip_bfloat16* ap = rh_bf + (size_t)am * H_ + quad * 8;
      const __hip_bfloat16* bp = WT + (size_t)bn * H_ + quad * 8;
#pragma unroll 4
      for (int kk = 0; kk < 32; ++kk) {
        short8 a = *(const short8*)(ap + kk * 32);
        short8 b = *(const short8*)(bp + kk * 32);
        acc = __builtin_amdgcn_mfma_f32_16x16x32_bf16(a, b, acc, 0, 0, 0);
      }
#pragma unroll
      for (int r = 0; r < 4; ++r) {
        int mm = wave * 16 + quad * 4 + r;
        int nn = nb + lr;
        float pre = acc[r] + G[(size_t)(t * B_ + mm) * 3072 + 2048 + nn];
        float hh = sigmoidf_(pre);
        float z = z_buf[mm * H_ + nn];
        float ho = h_state[mm * H_ + nn];
        float hn = ho + z * (hh - ho);
        h_state[mm * H_ + nn] = hn;
        h_bf[mm * H_ + nn] = __float2bfloat16(hn);
        Hseq[(size_t)(t * B_ + mm) * H_ + nn] = __float2bfloat16(hn);
        if (t == S_ - 1) h_final[mm * H_ + nn] = hn;
      }
    }
    gbar(bar_cnt, bar_gen, bidx++);
  }
}

// ---------------------------------- host launcher ---------------------------------------
extern "C" void kernel_launch(void* const* d_in, const int* in_sizes, int n_in,
                              void* d_out, int out_size, void* d_ws, size_t ws_size,
                              hipStream_t stream) {
  const int*   inputs      = (const int*)d_in[0];
  const float* init_hidden = (const float*)d_in[1];
  const float* emb         = (const float*)d_in[2];
  const float* Wr0 = (const float*)d_in[3];
  const float* Wz0 = (const float*)d_in[4];
  const float* Wh0 = (const float*)d_in[5];
  const float* br0 = (const float*)d_in[6];
  const float* bz0 = (const float*)d_in[7];
  const float* bh0 = (const float*)d_in[8];
  const float* Wr1 = (const float*)d_in[9];
  const float* Wz1 = (const float*)d_in[10];
  const float* Wh1 = (const float*)d_in[11];
  const float* br1 = (const float*)d_in[12];
  const float* bz1 = (const float*)d_in[13];
  const float* bh1 = (const float*)d_in[14];
  const float* Wfc0 = (const float*)d_in[15];
  const float* bfc0 = (const float*)d_in[16];
  const float* Wout = (const float*)d_in[17];
  const float* bout = (const float*)d_in[18];
  float* out = (float*)d_out;

  // -------- workspace layout --------
  char* ws = (char*)d_ws;
  size_t off = 0;
  auto alloc = [&](size_t bytes) -> char* {
    char* p = ws + off;
    off = (off + bytes + 255) & ~(size_t)255;
    return p;
  };
  int* bar = (int*)alloc(512);   // barrier state: [cnt0 @0, gen0 @32, cnt1 @64, gen1 @96]
  __hip_bfloat16* W0xT  = (__hip_bfloat16*)alloc((size_t)3072 * E_ * 2);
  __hip_bfloat16* W0hT  = (__hip_bfloat16*)alloc((size_t)3072 * H_ * 2);
  __hip_bfloat16* WfcT  = (__hip_bfloat16*)alloc((size_t)H_ * H_ * 2);
  __hip_bfloat16* W1xT  = (__hip_bfloat16*)alloc((size_t)3072 * H_ * 2);
  __hip_bfloat16* W1hT  = (__hip_bfloat16*)alloc((size_t)3072 * H_ * 2);
  __hip_bfloat16* WoutT = (__hip_bfloat16*)alloc((size_t)VPAD * H_ * 2);
  float* b0cat = (float*)alloc(3072 * 4);
  float* b1cat = (float*)alloc(3072 * 4);
  __hip_bfloat16* X0    = (__hip_bfloat16*)alloc((size_t)M_ * E_ * 2);
  float* G              = (float*)alloc((size_t)M_ * 3072 * 4);
  __hip_bfloat16* Hseq0 = (__hip_bfloat16*)alloc((size_t)M_ * H_ * 2);
  __hip_bfloat16* X1    = (__hip_bfloat16*)alloc((size_t)M_ * H_ * 2);
  __hip_bfloat16* Hseq1 = (__hip_bfloat16*)alloc((size_t)M_ * H_ * 2);
  float* hs0 = (float*)alloc((size_t)B_ * H_ * 4);
  float* hs1 = (float*)alloc((size_t)B_ * H_ * 4);
  __hip_bfloat16* hb0 = (__hip_bfloat16*)alloc((size_t)B_ * H_ * 2);
  __hip_bfloat16* hb1 = (__hip_bfloat16*)alloc((size_t)B_ * H_ * 2);
  __hip_bfloat16* rh  = (__hip_bfloat16*)alloc((size_t)B_ * H_ * 2);
  float* zb = (float*)alloc((size_t)B_ * H_ * 4);
  (void)ws_size; (void)n_in; (void)in_sizes; (void)out_size;

  // zero the barrier state (workspace is poisoned 0xAA before every launch)
  hipMemsetAsync(bar, 0, 512, stream);

  // -------- prep: biases, transposed bf16 weights, embedding --------
  hipLaunchKernelGGL(bias_concat, dim3(12), dim3(256), 0, stream,
                     br0, bz0, bh0, br1, bz1, bh1, b0cat, b1cat);

  auto tp = [&](const float* src, __hip_bfloat16* dst, int R, int C) {
    hipLaunchKernelGGL(transpose_cast, dim3((C + 31) / 32, (R + 31) / 32), dim3(256), 0,
                       stream, src, dst, R, C);
  };
  // layer 0 x-part [E,H] -> [3H, E]
  tp(Wr0,            W0xT,                E_, H_);
  tp(Wz0,            W0xT + 1024 * E_,    E_, H_);
  tp(Wh0,            W0xT + 2048 * E_,    E_, H_);
  // layer 0 h-part
  tp(Wr0 + (size_t)E_ * H_, W0hT,               H_, H_);
  tp(Wz0 + (size_t)E_ * H_, W0hT + 1024 * H_,   H_, H_);
  tp(Wh0 + (size_t)E_ * H_, W0hT + 2048 * H_,   H_, H_);
  // fc
  tp(Wfc0, WfcT, H_, H_);
  // layer 1 x-part
  tp(Wr1,            W1xT,                H_, H_);
  tp(Wz1,            W1xT + 1024 * H_,    H_, H_);
  tp(Wh1,            W1xT + 2048 * H_,    H_, H_);
  // layer 1 h-part
  tp(Wr1 + (size_t)H_ * H_, W1hT,               H_, H_);
  tp(Wz1 + (size_t)H_ * H_, W1hT + 1024 * H_,   H_, H_);
  tp(Wh1 + (size_t)H_ * H_, W1hT + 2048 * H_,   H_, H_);
  // out projection [H,V] -> [Vpad, H] (rows >= V left as poison, guarded at GEMM store)
  tp(Wout, WoutT, H_, V_);

  hipLaunchKernelGGL(embed_cast, dim3(M_ * (E_ / 4) / 256), dim3(256), 0, stream,
                     inputs, emb, X0);

  // -------- G0 = X0 @ W0x + b0cat  (fp32 [4096,3072]) --------
  hipLaunchKernelGGL(gemm_bf16, dim3(3072 / 64, M_ / 64), dim3(256), 0, stream,
                     X0, W0xT, b0cat, (void*)G, M_, 3072, E_, 0, 0);

  // -------- layer 0 recurrence --------
  {
    const float* Gp = G; const __hip_bfloat16* WTp = W0hT;
    const float* inith = init_hidden;                 // layer 0 slice
    float* hsp = hs0; __hip_bfloat16* hbp = hb0; __hip_bfloat16* rhp = rh;
    float* zbp = zb; __hip_bfloat16* Hsp = Hseq0;
    float* hfin = out + (size_t)M_ * V_;              // h_final layer 0
    int* c0 = bar; int* g0 = bar + 32;
    void* kargs[] = {(void*)&Gp, (void*)&WTp, (void*)&inith, (void*)&hsp, (void*)&hbp,
                     (void*)&rhp, (void*)&zbp, (void*)&Hsp, (void*)&hfin,
                     (void*)&c0, (void*)&g0};
    hipLaunchCooperativeKernel((const void*)gru_recurrent, dim3(NBLK), dim3(256),
                               kargs, 0, stream);
  }

  // -------- X1 = sigmoid(Hseq0 @ Wfc + bfc)  (bf16 [4096,1024]) --------
  hipLaunchKernelGGL(gemm_bf16, dim3(H_ / 64, M_ / 64), dim3(256), 0, stream,
                     Hseq0, WfcT, bfc0, (void*)X1, M_, H_, H_, 1, 1);

  // -------- G1 = X1 @ W1x + b1cat  (fp32 [4096,3072]) --------
  hipLaunchKernelGGL(gemm_bf16, dim3(3072 / 64, M_ / 64), dim3(256), 0, stream,
                     X1, W1xT, b1cat, (void*)G, M_, 3072, H_, 0, 0);

  // -------- layer 1 recurrence --------
  {
    const float* Gp = G; const __hip_bfloat16* WTp = W1hT;
    const float* inith = init_hidden + (size_t)B_ * H_;   // layer 1 slice
    float* hsp = hs1; __hip_bfloat16* hbp = hb1; __hip_bfloat16* rhp = rh;
    float* zbp = zb; __hip_bfloat16* Hsp = Hseq1;
    float* hfin = out + (size_t)M_ * V_ + (size_t)B_ * H_;  // h_final layer 1
    int* c1 = bar + 64; int* g1 = bar + 96;
    void* kargs[] = {(void*)&Gp, (void*)&WTp, (void*)&inith, (void*)&hsp, (void*)&hbp,
                     (void*)&rhp, (void*)&zbp, (void*)&Hsp, (void*)&hfin,
                     (void*)&c1, (void*)&g1};
    hipLaunchCooperativeKernel((const void*)gru_recurrent, dim3(NBLK), dim3(256),
                               kargs, 0, stream);
  }

  // -------- logits = Hseq1 @ Wout + bout  (fp32 [4096,10000] straight into d_out) -------
  hipLaunchKernelGGL(gemm_bf16, dim3(VPAD / 64, M_ / 64), dim3(256), 0, stream,
                     Hseq1, WoutT, bout, (void*)out, M_, V_, H_, 0, 0);
}

// Round 3
// 4426.267 us; speedup vs baseline: 1.5588x; 1.3231x over previous
//
#include <hip/hip_runtime.h>
#include <hip/hip_bf16.h>

typedef __attribute__((ext_vector_type(8))) short short8;
typedef __attribute__((ext_vector_type(4))) float f32x4;

#define S_ 64
#define B_ 64
#define H_ 1024
#define E_ 512
#define V_ 10000
#define M_ 4096          // S_*B_
#define VPAD 10048       // V rounded up to 64
#define NBLK 64

__device__ __forceinline__ float sigmoidf_(float x) {
  return 1.0f / (1.0f + __expf(-x));
}

// ---- fast device-scope grid barrier --------------------------------------------------
// Arrival: one ACQ_REL fetch_add (single wbl2+inv). Wait: RELAXED polls (no cache ops),
// then one ACQUIRE fence. cnt never resets; idx increments by 1 per call, uniform.
__device__ __forceinline__ void gbar(int* cnt, int* gen, int idx) {
  __syncthreads();
  if (threadIdx.x == 0) {
    int a = __hip_atomic_fetch_add(cnt, 1, __ATOMIC_ACQ_REL, __HIP_MEMORY_SCOPE_AGENT) + 1;
    if (a == NBLK * idx) {
      __hip_atomic_store(gen, idx, __ATOMIC_RELEASE, __HIP_MEMORY_SCOPE_AGENT);
    } else {
      while (__hip_atomic_load(gen, __ATOMIC_RELAXED, __HIP_MEMORY_SCOPE_AGENT) < idx) {
        __builtin_amdgcn_s_sleep(1);
      }
      __builtin_amdgcn_fence(__ATOMIC_ACQUIRE, "agent");
    }
  }
  __syncthreads();
}

// ---------------- bias concat: b0cat = [br0,bz0,bh0], b1cat = [br1,bz1,bh1] -------------
__global__ void bias_concat(const float* br0, const float* bz0, const float* bh0,
                            const float* br1, const float* bz1, const float* bh1,
                            float* b0cat, float* b1cat) {
  int i = blockIdx.x * 256 + threadIdx.x;   // 0..3071
  if (i >= 3072) return;
  if (i < 1024)       { b0cat[i] = br0[i];        b1cat[i] = br1[i]; }
  else if (i < 2048)  { b0cat[i] = bz0[i - 1024]; b1cat[i] = bz1[i - 1024]; }
  else                { b0cat[i] = bh0[i - 2048]; b1cat[i] = bh1[i - 2048]; }
}

// ---------------- transpose + cast: dst[c*R + r] = bf16(src[r*C + c]) -------------------
__global__ void transpose_cast(const float* __restrict__ src, __hip_bfloat16* __restrict__ dst,
                               int R, int C) {
  __shared__ float tile[32][33];
  int c0 = blockIdx.x * 32, r0 = blockIdx.y * 32;
  int tx = threadIdx.x & 31, ty = threadIdx.x >> 5;   // 32 x 8
#pragma unroll
  for (int i = 0; i < 4; ++i) {
    int r = r0 + ty + i * 8;
    int c = c0 + tx;
    if (r < R && c < C) tile[ty + i * 8][tx] = src[(size_t)r * C + c];
  }
  __syncthreads();
#pragma unroll
  for (int i = 0; i < 4; ++i) {
    int c = c0 + ty + i * 8;
    int r = r0 + tx;
    if (c < C && r < R) dst[(size_t)c * R + r] = __float2bfloat16(tile[tx][ty + i * 8]);
  }
}

// ---------------- embedding gather + cast to bf16: X0[i][e] = emb[tok[i]][e] ------------
__global__ void embed_cast(const int* __restrict__ inputs, const float* __restrict__ emb,
                           __hip_bfloat16* __restrict__ X0) {
  int idx = blockIdx.x * 256 + threadIdx.x;  // over 4096 * 128 float4 groups
  int i = idx >> 7;
  int e4 = idx & 127;
  int tok = inputs[i];
  const float4* src = (const float4*)(emb + (size_t)tok * E_);
  float4 v = src[e4];
  __hip_bfloat16* dst = X0 + (size_t)i * E_ + e4 * 4;
  dst[0] = __float2bfloat16(v.x);
  dst[1] = __float2bfloat16(v.y);
  dst[2] = __float2bfloat16(v.z);
  dst[3] = __float2bfloat16(v.w);
}

// ---------------- generic bf16 MFMA GEMM: C = act(A[M,K] @ BT[N,K]^T + bias) ------------
// grid = (ceil(N/64), M/64), block = 256 (4 waves, each a 32x32 quadrant of the 64x64 tile)
__global__ __launch_bounds__(256) void gemm_bf16(
    const __hip_bfloat16* __restrict__ A, const __hip_bfloat16* __restrict__ BT,
    const float* __restrict__ bias, void* __restrict__ C,
    int M, int N, int K, int act, int out_bf16) {
  __shared__ unsigned short Al[64 * 72];
  __shared__ unsigned short Bl[64 * 72];
  const int m0 = blockIdx.y * 64, n0 = blockIdx.x * 64;
  const int tid = threadIdx.x;
  const int wave = tid >> 6, lane = tid & 63;
  const int quad = lane >> 4, lr = lane & 15;
  const int wm = (wave >> 1) * 32, wn = (wave & 1) * 32;
  const int srow = tid >> 2, scol = (tid & 3) << 4;

  f32x4 acc[2][2];
#pragma unroll
  for (int a = 0; a < 2; ++a)
#pragma unroll
    for (int b = 0; b < 2; ++b) acc[a][b] = (f32x4){0.f, 0.f, 0.f, 0.f};

  const __hip_bfloat16* Ag = A + (size_t)(m0 + srow) * K + scol;
  const __hip_bfloat16* Bg = BT + (size_t)(n0 + srow) * K + scol;

  for (int kb = 0; kb < K; kb += 64) {
    short8 a0 = *(const short8*)(Ag + kb);
    short8 a1 = *(const short8*)(Ag + kb + 8);
    short8 b0 = *(const short8*)(Bg + kb);
    short8 b1 = *(const short8*)(Bg + kb + 8);
    *(short8*)&Al[srow * 72 + scol] = a0;
    *(short8*)&Al[srow * 72 + scol + 8] = a1;
    *(short8*)&Bl[srow * 72 + scol] = b0;
    *(short8*)&Bl[srow * 72 + scol + 8] = b1;
    __syncthreads();
#pragma unroll
    for (int k2 = 0; k2 < 64; k2 += 32) {
      short8 af0 = *(const short8*)&Al[(wm + lr) * 72 + k2 + quad * 8];
      short8 af1 = *(const short8*)&Al[(wm + 16 + lr) * 72 + k2 + quad * 8];
      short8 bf0 = *(const short8*)&Bl[(wn + lr) * 72 + k2 + quad * 8];
      short8 bf1 = *(const short8*)&Bl[(wn + 16 + lr) * 72 + k2 + quad * 8];
      acc[0][0] = __builtin_amdgcn_mfma_f32_16x16x32_bf16(af0, bf0, acc[0][0], 0, 0, 0);
      acc[0][1] = __builtin_amdgcn_mfma_f32_16x16x32_bf16(af0, bf1, acc[0][1], 0, 0, 0);
      acc[1][0] = __builtin_amdgcn_mfma_f32_16x16x32_bf16(af1, bf0, acc[1][0], 0, 0, 0);
      acc[1][1] = __builtin_amdgcn_mfma_f32_16x16x32_bf16(af1, bf1, acc[1][1], 0, 0, 0);
    }
    __syncthreads();
  }

#pragma unroll
  for (int mi = 0; mi < 2; ++mi)
#pragma unroll
    for (int ni = 0; ni < 2; ++ni) {
      int n = n0 + wn + ni * 16 + lr;
      if (n >= N) continue;
      float bv = bias ? bias[n] : 0.f;
#pragma unroll
      for (int r = 0; r < 4; ++r) {
        int m = m0 + wm + mi * 16 + quad * 4 + r;
        float v = acc[mi][ni][r] + bv;
        if (act) v = sigmoidf_(v);
        if (out_bf16) ((__hip_bfloat16*)C)[(size_t)m * N + n] = __float2bfloat16(v);
        else          ((float*)C)[(size_t)m * N + n] = v;
      }
    }
}

// ---------------- cooperative GRU recurrence for one layer ------------------------------
// G:   [4096, 3072] fp32 pre-activation x-part (+bias), cols (r, z, hh)
// WT:  [3072, 1024] bf16 transposed h-part weights, rows (r, z, hh)
// 64 blocks x 256 threads. Phase A: 32 cols each of rz (2048).
// Phase B: 16 cols each of hh (1024).
__global__ __launch_bounds__(256) void gru_recurrent(
    const float* __restrict__ G, const __hip_bfloat16* __restrict__ WT,
    const float* __restrict__ init_h,
    float* __restrict__ h_state, __hip_bfloat16* __restrict__ h_bf,
    __hip_bfloat16* __restrict__ rh_bf, float* __restrict__ z_buf,
    __hip_bfloat16* __restrict__ Hseq, float* __restrict__ h_final,
    int* __restrict__ bar_cnt, int* __restrict__ bar_gen) {
  const int bid = blockIdx.x;
  const int tid = threadIdx.x;
  const int wave = tid >> 6, lane = tid & 63;
  const int quad = lane >> 4, lr = lane & 15;

  // init h_state / h_bf from init_hidden
  for (int idx = bid * 256 + tid; idx < B_ * H_; idx += NBLK * 256) {
    float v = init_h[idx];
    h_state[idx] = v;
    h_bf[idx] = __float2bfloat16(v);
  }
  int bidx = 1;
  gbar(bar_cnt, bar_gen, bidx++);

  for (int t = 0; t < S_; ++t) {
    // ---- phase A: rz = sigmoid(G_rz[t] + h @ W_rz), 32 cols per block ----
    {
      const int nb = bid * 32;
      const int am = wave * 16 + lr;   // A row this lane loads (batch)
      f32x4 acc0 = (f32x4){0.f, 0.f, 0.f, 0.f};
      f32x4 acc1 = (f32x4){0.f, 0.f, 0.f, 0.f};
      const __hip_bfloat16* ap = h_bf + (size_t)am * H_ + quad * 8;
      const __hip_bfloat16* bp0 = WT + (size_t)(nb + lr) * H_ + quad * 8;
      const __hip_bfloat16* bp1 = WT + (size_t)(nb + 16 + lr) * H_ + quad * 8;
      // prefetch G values for the epilogue (hide latency under MFMA chain)
      float g0[4], g1[4];
#pragma unroll
      for (int r = 0; r < 4; ++r) {
        int mm = wave * 16 + quad * 4 + r;
        g0[r] = G[(size_t)(t * B_ + mm) * 3072 + nb + lr];
        g1[r] = G[(size_t)(t * B_ + mm) * 3072 + nb + 16 + lr];
      }
#pragma unroll 4
      for (int kk = 0; kk < 32; ++kk) {
        short8 a = *(const short8*)(ap + kk * 32);
        short8 b0 = *(const short8*)(bp0 + kk * 32);
        short8 b1 = *(const short8*)(bp1 + kk * 32);
        acc0 = __builtin_amdgcn_mfma_f32_16x16x32_bf16(a, b0, acc0, 0, 0, 0);
        acc1 = __builtin_amdgcn_mfma_f32_16x16x32_bf16(a, b1, acc1, 0, 0, 0);
      }
#pragma unroll
      for (int r = 0; r < 4; ++r) {
        int mm = wave * 16 + quad * 4 + r;
#pragma unroll
        for (int half = 0; half < 2; ++half) {
          int nn = nb + half * 16 + lr;
          float val = (half ? acc1[r] + g1[r] : acc0[r] + g0[r]);
          val = sigmoidf_(val);
          if (nn < H_) {
            rh_bf[mm * H_ + nn] = __float2bfloat16(val * h_state[mm * H_ + nn]);
          } else {
            z_buf[mm * H_ + (nn - H_)] = val;
          }
        }
      }
    }
    gbar(bar_cnt, bar_gen, bidx++);
    // ---- phase B: hh = sigmoid(G_h[t] + (r*h) @ Wh_h); h = (1-z)h + z*hh ----
    {
      const int nb = bid * 16;
      const int am = wave * 16 + lr;
      const int bn = 2048 + nb + lr;
      f32x4 acc = (f32x4){0.f, 0.f, 0.f, 0.f};
      const __hip_bfloat16* ap = rh_bf + (size_t)am * H_ + quad * 8;
      const __hip_bfloat16* bp = WT + (size_t)bn * H_ + quad * 8;
      float gh[4], zv[4], hv[4];
#pragma unroll
      for (int r = 0; r < 4; ++r) {
        int mm = wave * 16 + quad * 4 + r;
        int nn = nb + lr;
        gh[r] = G[(size_t)(t * B_ + mm) * 3072 + 2048 + nn];
        zv[r] = z_buf[mm * H_ + nn];
        hv[r] = h_state[mm * H_ + nn];
      }
#pragma unroll 4
      for (int kk = 0; kk < 32; ++kk) {
        short8 a = *(const short8*)(ap + kk * 32);
        short8 b = *(const short8*)(bp + kk * 32);
        acc = __builtin_amdgcn_mfma_f32_16x16x32_bf16(a, b, acc, 0, 0, 0);
      }
#pragma unroll
      for (int r = 0; r < 4; ++r) {
        int mm = wave * 16 + quad * 4 + r;
        int nn = nb + lr;
        float hh = sigmoidf_(acc[r] + gh[r]);
        float hn = hv[r] + zv[r] * (hh - hv[r]);
        h_state[mm * H_ + nn] = hn;
        h_bf[mm * H_ + nn] = __float2bfloat16(hn);
        Hseq[(size_t)(t * B_ + mm) * H_ + nn] = __float2bfloat16(hn);
        if (t == S_ - 1) h_final[mm * H_ + nn] = hn;
      }
    }
    gbar(bar_cnt, bar_gen, bidx++);
  }
}

// ---------------------------------- host launcher ---------------------------------------
extern "C" void kernel_launch(void* const* d_in, const int* in_sizes, int n_in,
                              void* d_out, int out_size, void* d_ws, size_t ws_size,
                              hipStream_t stream) {
  const int*   inputs      = (const int*)d_in[0];
  const float* init_hidden = (const float*)d_in[1];
  const float* emb         = (const float*)d_in[2];
  const float* Wr0 = (const float*)d_in[3];
  const float* Wz0 = (const float*)d_in[4];
  const float* Wh0 = (const float*)d_in[5];
  const float* br0 = (const float*)d_in[6];
  const float* bz0 = (const float*)d_in[7];
  const float* bh0 = (const float*)d_in[8];
  const float* Wr1 = (const float*)d_in[9];
  const float* Wz1 = (const float*)d_in[10];
  const float* Wh1 = (const float*)d_in[11];
  const float* br1 = (const float*)d_in[12];
  const float* bz1 = (const float*)d_in[13];
  const float* bh1 = (const float*)d_in[14];
  const float* Wfc0 = (const float*)d_in[15];
  const float* bfc0 = (const float*)d_in[16];
  const float* Wout = (const float*)d_in[17];
  const float* bout = (const float*)d_in[18];
  float* out = (float*)d_out;

  // -------- workspace layout --------
  char* ws = (char*)d_ws;
  size_t off = 0;
  auto alloc = [&](size_t bytes) -> char* {
    char* p = ws + off;
    off = (off + bytes + 255) & ~(size_t)255;
    return p;
  };
  int* bar = (int*)alloc(512);   // barrier state: [cnt0 @0, gen0 @32, cnt1 @64, gen1 @96]
  __hip_bfloat16* W0xT  = (__hip_bfloat16*)alloc((size_t)3072 * E_ * 2);
  __hip_bfloat16* W0hT  = (__hip_bfloat16*)alloc((size_t)3072 * H_ * 2);
  __hip_bfloat16* WfcT  = (__hip_bfloat16*)alloc((size_t)H_ * H_ * 2);
  __hip_bfloat16* W1xT  = (__hip_bfloat16*)alloc((size_t)3072 * H_ * 2);
  __hip_bfloat16* W1hT  = (__hip_bfloat16*)alloc((size_t)3072 * H_ * 2);
  __hip_bfloat16* WoutT = (__hip_bfloat16*)alloc((size_t)VPAD * H_ * 2);
  float* b0cat = (float*)alloc(3072 * 4);
  float* b1cat = (float*)alloc(3072 * 4);
  __hip_bfloat16* X0    = (__hip_bfloat16*)alloc((size_t)M_ * E_ * 2);
  float* G              = (float*)alloc((size_t)M_ * 3072 * 4);
  __hip_bfloat16* Hseq0 = (__hip_bfloat16*)alloc((size_t)M_ * H_ * 2);
  __hip_bfloat16* X1    = (__hip_bfloat16*)alloc((size_t)M_ * H_ * 2);
  __hip_bfloat16* Hseq1 = (__hip_bfloat16*)alloc((size_t)M_ * H_ * 2);
  float* hs0 = (float*)alloc((size_t)B_ * H_ * 4);
  float* hs1 = (float*)alloc((size_t)B_ * H_ * 4);
  __hip_bfloat16* hb0 = (__hip_bfloat16*)alloc((size_t)B_ * H_ * 2);
  __hip_bfloat16* hb1 = (__hip_bfloat16*)alloc((size_t)B_ * H_ * 2);
  __hip_bfloat16* rh  = (__hip_bfloat16*)alloc((size_t)B_ * H_ * 2);
  float* zb = (float*)alloc((size_t)B_ * H_ * 4);
  (void)ws_size; (void)n_in; (void)in_sizes; (void)out_size;

  // zero the barrier state (workspace is poisoned 0xAA before every launch)
  hipMemsetAsync(bar, 0, 512, stream);

  // -------- prep: biases, transposed bf16 weights, embedding --------
  hipLaunchKernelGGL(bias_concat, dim3(12), dim3(256), 0, stream,
                     br0, bz0, bh0, br1, bz1, bh1, b0cat, b1cat);

  auto tp = [&](const float* src, __hip_bfloat16* dst, int R, int C) {
    hipLaunchKernelGGL(transpose_cast, dim3((C + 31) / 32, (R + 31) / 32), dim3(256), 0,
                       stream, src, dst, R, C);
  };
  // layer 0 x-part [E,H] -> [3H, E]
  tp(Wr0,            W0xT,                E_, H_);
  tp(Wz0,            W0xT + 1024 * E_,    E_, H_);
  tp(Wh0,            W0xT + 2048 * E_,    E_, H_);
  // layer 0 h-part
  tp(Wr0 + (size_t)E_ * H_, W0hT,               H_, H_);
  tp(Wz0 + (size_t)E_ * H_, W0hT + 1024 * H_,   H_, H_);
  tp(Wh0 + (size_t)E_ * H_, W0hT + 2048 * H_,   H_, H_);
  // fc
  tp(Wfc0, WfcT, H_, H_);
  // layer 1 x-part
  tp(Wr1,            W1xT,                H_, H_);
  tp(Wz1,            W1xT + 1024 * H_,    H_, H_);
  tp(Wh1,            W1xT + 2048 * H_,    H_, H_);
  // layer 1 h-part
  tp(Wr1 + (size_t)H_ * H_, W1hT,               H_, H_);
  tp(Wz1 + (size_t)H_ * H_, W1hT + 1024 * H_,   H_, H_);
  tp(Wh1 + (size_t)H_ * H_, W1hT + 2048 * H_,   H_, H_);
  // out projection [H,V] -> [Vpad, H] (rows >= V left as poison, guarded at GEMM store)
  tp(Wout, WoutT, H_, V_);

  hipLaunchKernelGGL(embed_cast, dim3(M_ * (E_ / 4) / 256), dim3(256), 0, stream,
                     inputs, emb, X0);

  // -------- G0 = X0 @ W0x + b0cat  (fp32 [4096,3072]) --------
  hipLaunchKernelGGL(gemm_bf16, dim3(3072 / 64, M_ / 64), dim3(256), 0, stream,
                     X0, W0xT, b0cat, (void*)G, M_, 3072, E_, 0, 0);

  // -------- layer 0 recurrence --------
  {
    const float* Gp = G; const __hip_bfloat16* WTp = W0hT;
    const float* inith = init_hidden;                 // layer 0 slice
    float* hsp = hs0; __hip_bfloat16* hbp = hb0; __hip_bfloat16* rhp = rh;
    float* zbp = zb; __hip_bfloat16* Hsp = Hseq0;
    float* hfin = out + (size_t)M_ * V_;              // h_final layer 0
    int* c0 = bar; int* g0 = bar + 32;
    void* kargs[] = {(void*)&Gp, (void*)&WTp, (void*)&inith, (void*)&hsp, (void*)&hbp,
                     (void*)&rhp, (void*)&zbp, (void*)&Hsp, (void*)&hfin,
                     (void*)&c0, (void*)&g0};
    hipLaunchCooperativeKernel((const void*)gru_recurrent, dim3(NBLK), dim3(256),
                               kargs, 0, stream);
  }

  // -------- X1 = sigmoid(Hseq0 @ Wfc + bfc)  (bf16 [4096,1024]) --------
  hipLaunchKernelGGL(gemm_bf16, dim3(H_ / 64, M_ / 64), dim3(256), 0, stream,
                     Hseq0, WfcT, bfc0, (void*)X1, M_, H_, H_, 1, 1);

  // -------- G1 = X1 @ W1x + b1cat  (fp32 [4096,3072]) --------
  hipLaunchKernelGGL(gemm_bf16, dim3(3072 / 64, M_ / 64), dim3(256), 0, stream,
                     X1, W1xT, b1cat, (void*)G, M_, 3072, H_, 0, 0);

  // -------- layer 1 recurrence --------
  {
    const float* Gp = G; const __hip_bfloat16* WTp = W1hT;
    const float* inith = init_hidden + (size_t)B_ * H_;   // layer 1 slice
    float* hsp = hs1; __hip_bfloat16* hbp = hb1; __hip_bfloat16* rhp = rh;
    float* zbp = zb; __hip_bfloat16* Hsp = Hseq1;
    float* hfin = out + (size_t)M_ * V_ + (size_t)B_ * H_;  // h_final layer 1
    int* c1 = bar + 64; int* g1 = bar + 96;
    void* kargs[] = {(void*)&Gp, (void*)&WTp, (void*)&inith, (void*)&hsp, (void*)&hbp,
                     (void*)&rhp, (void*)&zbp, (void*)&Hsp, (void*)&hfin,
                     (void*)&c1, (void*)&g1};
    hipLaunchCooperativeKernel((const void*)gru_recurrent, dim3(NBLK), dim3(256),
                               kargs, 0, stream);
  }

  // -------- logits = Hseq1 @ Wout + bout  (fp32 [4096,10000] straight into d_out) -------
  hipLaunchKernelGGL(gemm_bf16, dim3(VPAD / 64, M_ / 64), dim3(256), 0, stream,
                     Hseq1, WoutT, bout, (void*)out, M_, V_, H_, 0, 0);
}